// Round 2
// baseline (878.525 us; speedup 1.0000x reference)
//
#include <hip/hip_runtime.h>

#define B_TOTAL 262144
#define D_IN 512
#define LN_EPS 1e-5f

typedef __attribute__((ext_vector_type(8))) short short8;
typedef __attribute__((ext_vector_type(4))) float f32x4;

// Native RNE f32->bf16: compiler emits v_cvt_pk_bf16_f32 for adjacent pairs
// (guide §5.5 T12 / m240: scalar casts beat hand bit-twiddling).
// Bit-identical to the old hand-rolled RNE for finite inputs.
__device__ __forceinline__ short f2bf(float f) {
    __bf16 h = (__bf16)f;
    unsigned short u;
    __builtin_memcpy(&u, &h, sizeof(u));
    return (short)u;
}

__device__ __forceinline__ short8 cvt8(f32x4 lo, f32x4 hi) {
    short8 r;
    r[0] = f2bf(lo[0]); r[1] = f2bf(lo[1]);
    r[2] = f2bf(lo[2]); r[3] = f2bf(lo[3]);
    r[4] = f2bf(hi[0]); r[5] = f2bf(hi[1]);
    r[6] = f2bf(hi[2]); r[7] = f2bf(hi[3]);
    return r;
}

// Round-0 proven structure: 4096 blocks x 256 threads, 64 samples/block,
// no workspace (d_ws is poisoned by the harness inside the timed region —
// never carry state in it across kernel boundaries; round-1 lesson).
__global__ __launch_bounds__(256) void faiia_kernel(
    const float* __restrict__ x,       // [B, 512] fp32
    const float* __restrict__ mprob,   // [B]
    const float* __restrict__ Wq,      // [32, 512]
    const float* __restrict__ bq,      // [32]
    const float* __restrict__ pk,      // [4, 32]
    const float* __restrict__ pv,      // [4, 32]
    const float* __restrict__ imp,     // [4]
    const float* __restrict__ falpha,  // [1]
    const float* __restrict__ ftemp,   // [1]
    const float* __restrict__ Wo,      // [32, 32]
    const float* __restrict__ bo,      // [32]
    const float* __restrict__ gamma,   // [32]
    const float* __restrict__ beta,    // [32]
    float* __restrict__ out)           // [B*32] out ++ [B*4] weights
{
    // pitch 36: rows 16B-aligned (144 B) so tail reads are ds_read_b128;
    // bank pattern is <=2-way aliased which is free (learn_hip m136).
    __shared__ __align__(16) float lds_q[64][36];
    __shared__ __align__(16) float lds_att[64][36];

    const int tid  = threadIdx.x;
    const int wave = tid >> 6;
    const int lane = tid & 63;
    const int blockBase = blockIdx.x * 64;

    // ================= MFMA projection: q = x @ Wq^T =================
    // mfma_f32_16x16x32_bf16 layouts (HW-verified, learn_hip m89/m120):
    //   A[m = lane&15][k = quad*8 + j]
    //   B[k = quad*8 + j][n = lane&15]  == Wq[n][k], 8 contiguous k
    //   D[row = quad*4 + reg][col = lane&15]  (row = sample, col = att dim)
    const int m    = lane & 15;
    const int quad = lane >> 4;
    const int row  = blockBase + wave * 16 + m;

    const float* ax  = x  + (size_t)row * D_IN + quad * 8;
    const float* bw0 = Wq + (size_t)m   * D_IN + quad * 8;  // n = lane&15
    const float* bw1 = bw0 + 16 * D_IN;                      // n = lane&15 + 16

    f32x4 acc0 = {0.f, 0.f, 0.f, 0.f};
    f32x4 acc1 = {0.f, 0.f, 0.f, 0.f};
    #pragma unroll
    for (int kk = 0; kk < 16; ++kk) {
        // x streamed exactly once -> nontemporal keeps L2 for Wq + constants
        f32x4 a0 = __builtin_nontemporal_load((const f32x4*)(ax + kk * 32));
        f32x4 a1 = __builtin_nontemporal_load((const f32x4*)(ax + kk * 32 + 4));
        f32x4 p0 = *(const f32x4*)(bw0 + kk * 32);
        f32x4 p1 = *(const f32x4*)(bw0 + kk * 32 + 4);
        f32x4 r0 = *(const f32x4*)(bw1 + kk * 32);
        f32x4 r1 = *(const f32x4*)(bw1 + kk * 32 + 4);
        short8 a  = cvt8(a0, a1);     // 4x v_cvt_pk_bf16_f32 each
        short8 b0 = cvt8(p0, p1);
        short8 b1 = cvt8(r0, r1);
        acc0 = __builtin_amdgcn_mfma_f32_16x16x32_bf16(a, b0, acc0, 0, 0, 0);
        acc1 = __builtin_amdgcn_mfma_f32_16x16x32_bf16(a, b1, acc1, 0, 0, 0);
    }

    {
        const float bq0 = bq[m];
        const float bq1 = bq[m + 16];
        #pragma unroll
        for (int r = 0; r < 4; ++r) {
            int s = wave * 16 + quad * 4 + r;   // local sample index
            lds_q[s][m]      = acc0[r] + bq0;
            lds_q[s][m + 16] = acc1[r] + bq1;
        }
    }
    __syncthreads();

    // ============ per-sample tail: 4 threads / sample, fp32 exact ============
    const int sLocal = tid >> 2;       // 0..63
    const int part   = tid & 3;        // owns dims part*8 .. part*8+7
    const int d0     = part * 8;
    const int sample = blockBase + sLocal;

    // two ds_read_b128 (row base 144*sLocal is 16B-aligned, d0*4 = 32*part)
    const f32x4 q0v = *(const f32x4*)&lds_q[sLocal][d0];
    const f32x4 q1v = *(const f32x4*)&lds_q[sLocal][d0 + 4];

    // scores = q @ pk^T + importance (reduce partials over the 4-lane group)
    float sc[4];
    #pragma unroll
    for (int p = 0; p < 4; ++p) {
        const f32x4 k0 = *(const f32x4*)(pk + p * 32 + d0);
        const f32x4 k1 = *(const f32x4*)(pk + p * 32 + d0 + 4);
        float s = q0v[0]*k0[0] + q0v[1]*k0[1] + q0v[2]*k0[2] + q0v[3]*k0[3]
                + q1v[0]*k1[0] + q1v[1]*k1[1] + q1v[2]*k1[2] + q1v[3]*k1[3];
        s += __shfl_xor(s, 1);
        s += __shfl_xor(s, 2);
        sc[p] = s + imp[p];
    }

    // focal modulation (GAMMA=2 -> square)
    const float prob = mprob[sample];
    const float unc  = 1.f - fabsf(prob - 0.5f) * 2.f;
    const float ue   = unc + 1e-8f;
    const float fw   = falpha[0] * ue * ue * ftemp[0];
    const float SCALE = 0.1767766952966369f;   // 32^-0.5
    const float mult  = (1.f + fw) * SCALE;

    // softmax over 4 prototypes (expf kept for exact round-0 numerics)
    float z[4];
    #pragma unroll
    for (int p = 0; p < 4; ++p) z[p] = sc[p] * mult;
    float zmax = fmaxf(fmaxf(z[0], z[1]), fmaxf(z[2], z[3]));
    float w[4], wsum = 0.f;
    #pragma unroll
    for (int p = 0; p < 4; ++p) { w[p] = expf(z[p] - zmax); wsum += w[p]; }
    const float winv = 1.f / wsum;
    #pragma unroll
    for (int p = 0; p < 4; ++p) w[p] *= winv;

    // attended = weights @ proto_values (our 8 dims), broadcast via LDS
    f32x4 alo, ahi;
    #pragma unroll
    for (int j = 0; j < 4; ++j) {
        const int n = d0 + j;
        alo[j] = w[0]*pv[n] + w[1]*pv[32 + n] + w[2]*pv[64 + n] + w[3]*pv[96 + n];
    }
    #pragma unroll
    for (int j = 0; j < 4; ++j) {
        const int n = d0 + 4 + j;
        ahi[j] = w[0]*pv[n] + w[1]*pv[32 + n] + w[2]*pv[64 + n] + w[3]*pv[96 + n];
    }
    *(f32x4*)&lds_att[sLocal][d0]     = alo;   // ds_write_b128
    *(f32x4*)&lds_att[sLocal][d0 + 4] = ahi;
    __syncthreads();

    f32x4 attv[8];
    #pragma unroll
    for (int c = 0; c < 8; ++c)
        attv[c] = *(const f32x4*)&lds_att[sLocal][c * 4];   // ds_read_b128

    // out = attended @ Wo^T + bo (our 8 output dims), Wo rows as f32x4
    float o[8];
    #pragma unroll
    for (int jo = 0; jo < 8; ++jo) {
        const int n2 = d0 + jo;
        const f32x4* wrow = (const f32x4*)(Wo + n2 * 32);
        float s = bo[n2];
        #pragma unroll
        for (int c = 0; c < 8; ++c) {
            f32x4 wv = wrow[c];
            s += attv[c][0]*wv[0] + attv[c][1]*wv[1]
               + attv[c][2]*wv[2] + attv[c][3]*wv[3];
        }
        o[jo] = s;
    }

    // LayerNorm over 32 dims (population var), partials over 4 lanes
    float s1 = 0.f, s2 = 0.f;
    #pragma unroll
    for (int jo = 0; jo < 8; ++jo) { s1 += o[jo]; s2 += o[jo] * o[jo]; }
    s1 += __shfl_xor(s1, 1); s1 += __shfl_xor(s1, 2);
    s2 += __shfl_xor(s2, 1); s2 += __shfl_xor(s2, 2);
    const float mu   = s1 * (1.f / 32.f);
    const float var  = s2 * (1.f / 32.f) - mu * mu;
    const float rstd = rsqrtf(var + LN_EPS);

    f32x4 res_lo, res_hi;
    #pragma unroll
    for (int jo = 0; jo < 8; ++jo) {
        const int n2 = d0 + jo;
        float y = (o[jo] - mu) * rstd * gamma[n2] + beta[n2];
        if (jo < 4) res_lo[jo] = y; else res_hi[jo - 4] = y;
    }
    // 32 B coalesced nontemporal store per thread (out is write-once)
    __builtin_nontemporal_store(res_lo, (f32x4*)(out + (size_t)sample * 32 + d0));
    __builtin_nontemporal_store(res_hi, (f32x4*)(out + (size_t)sample * 32 + d0 + 4));

    if (part == 0) {
        f32x4 wres;
        #pragma unroll
        for (int p = 0; p < 4; ++p) wres[p] = w[p];
        __builtin_nontemporal_store(wres,
            (f32x4*)(out + (size_t)B_TOTAL * 32 + (size_t)sample * 4));
    }
}

extern "C" void kernel_launch(void* const* d_in, const int* in_sizes, int n_in,
                              void* d_out, int out_size, void* d_ws, size_t ws_size,
                              hipStream_t stream) {
    const float* x      = (const float*)d_in[0];
    const float* mprob  = (const float*)d_in[1];
    const float* Wq     = (const float*)d_in[2];
    const float* bq     = (const float*)d_in[3];
    const float* pk     = (const float*)d_in[4];
    const float* pv     = (const float*)d_in[5];
    const float* imp    = (const float*)d_in[6];
    const float* falpha = (const float*)d_in[7];
    const float* ftemp  = (const float*)d_in[8];
    const float* Wo     = (const float*)d_in[9];
    const float* bo     = (const float*)d_in[10];
    const float* gamma  = (const float*)d_in[11];
    const float* beta   = (const float*)d_in[12];
    float* out = (float*)d_out;

    const int blocks = B_TOTAL / 64;   // 4096 blocks, 64 samples each
    faiia_kernel<<<blocks, 256, 0, stream>>>(
        x, mprob, Wq, bq, pk, pv, imp, falpha, ftemp, Wo, bo, gamma, beta, out);
}

// Round 3
// 810.221 us; speedup vs baseline: 1.0843x; 1.0843x over previous
//
#include <hip/hip_runtime.h>

#define B_TOTAL 262144
#define D_IN 512
#define LN_EPS 1e-5f

typedef __attribute__((ext_vector_type(8))) short short8;
typedef __attribute__((ext_vector_type(4))) float f32x4;

// Native RNE f32->bf16: pairs fuse to v_cvt_pk_bf16_f32 (guide m240).
__device__ __forceinline__ short f2bf(float f) {
    __bf16 h = (__bf16)f;
    unsigned short u;
    __builtin_memcpy(&u, &h, sizeof(u));
    return (short)u;
}

__device__ __forceinline__ short8 cvt8(f32x4 lo, f32x4 hi) {
    short8 r;
    r[0] = f2bf(lo[0]); r[1] = f2bf(lo[1]);
    r[2] = f2bf(lo[2]); r[3] = f2bf(lo[3]);
    r[4] = f2bf(hi[0]); r[5] = f2bf(hi[1]);
    r[6] = f2bf(hi[2]); r[7] = f2bf(hi[3]);
    return r;
}

// async global->LDS, 16 B/lane; LDS dest = wave-uniform base + lane*16 (m104)
#define GLL(g, l) __builtin_amdgcn_global_load_lds(                      \
    (const __attribute__((address_space(1))) void*)(g),                  \
    (__attribute__((address_space(3))) void*)(l), 16, 0, 0)

__global__ __launch_bounds__(256) void faiia_kernel(
    const float* __restrict__ x,       // [B, 512] fp32
    const float* __restrict__ mprob,   // [B]
    const float* __restrict__ Wq,      // [32, 512]
    const float* __restrict__ bq,      // [32]
    const float* __restrict__ pk,      // [4, 32]
    const float* __restrict__ pv,      // [4, 32]
    const float* __restrict__ imp,     // [4]
    const float* __restrict__ falpha,  // [1]
    const float* __restrict__ ftemp,   // [1]
    const float* __restrict__ Wo,      // [32, 32]
    const float* __restrict__ bo,      // [32]
    const float* __restrict__ gamma,   // [32]
    const float* __restrict__ beta,    // [32]
    float* __restrict__ out)           // [B*32] out ++ [B*4] weights
{
    // 64 KB static LDS:
    //  [0, 32768):      Wq bf16 fragments: frag(s,a,lane) at s*2048 + a*1024 + lane*16 B
    //  [32768, 65536):  x pipeline, 4 slices x 8192 B;
    //                   within a slice: wave region w*2048, half j*1024, lane l*16
    //  x region is reused after the loop (post-barrier) for lds_q / lds_att.
    __shared__ __align__(16) char smem[65536];
    short* wq_lds = (short*)smem;
    float* xbuf   = (float*)(smem + 32768);
    float (*lds_q)[33]   = (float(*)[33])(smem + 32768);          // 8448 B
    float (*lds_att)[33] = (float(*)[33])(smem + 32768 + 8448);   // 8448 B

    const int tid  = threadIdx.x;
    const int wave = tid >> 6;
    const int lane = tid & 63;
    const int blockBase = blockIdx.x * 64;

    // mfma_f32_16x16x32_bf16 layouts (HW-verified, learn_hip m89/m120):
    //   A[m = lane&15][k = quad*8 + j] ; B[k][n = lane&15] ; D[quad*4+reg][lane&15]
    const int m    = lane & 15;
    const int quad = lane >> 4;

    // per-lane global source of this lane's A fragment: row (w*16+m), k-chunk quad*8
    const float* xrow = x + (size_t)(blockBase + wave * 16 + m) * D_IN + quad * 8;
    float* xw = xbuf + wave * 512;   // this wave's slice region (floats)

    // ---- prologue: issue x slices 0..2 (HBM latency hides under Wq staging) ----
    #pragma unroll
    for (int t = 0; t < 3; ++t) {
        float* d = xw + t * 2048;               // slice t (t&3 == t), wave region
        GLL(xrow + t * 32,     d);              // lo halves: k = q*8 + 0..3
        GLL(xrow + t * 32 + 4, d + 256);        // hi halves: k = q*8 + 4..7
    }

    // ---- stage Wq once per block as bf16 MFMA fragments ----
    // chunk id -> row n = id>>6, col-chunk c = id&63 (8 floats);
    // fragment coords: s = c>>2, q = c&3, dest lane = q*16 + (n&15), a = n>>4
    #pragma unroll
    for (int it = 0; it < 8; ++it) {
        const int id = it * 256 + tid;
        const int n  = id >> 6;
        const int c  = id & 63;
        f32x4 v0 = *(const f32x4*)(Wq + n * 512 + c * 8);
        f32x4 v1 = *(const f32x4*)(Wq + n * 512 + c * 8 + 4);
        const int sk = c >> 2, q = c & 3;
        const int ld = q * 16 + (n & 15);
        const int a  = n >> 4;
        *(short8*)(wq_lds + sk * 1024 + a * 512 + ld * 8) = cvt8(v0, v1);
    }
    __syncthreads();   // wq_lds visible to all waves; drains vmcnt -> exact baseline

    // ---- MFMA K-loop: barrier-free, counted vmcnt (never 0 until drain) ----
    const float* myl = xbuf + wave * 512 + lane * 4;  // + (s&3)*2048 ; hi at +256
    const short* bfr = wq_lds + lane * 8;             // + s*1024 ; b1 at +512

    f32x4 acc0 = {0.f, 0.f, 0.f, 0.f};
    f32x4 acc1 = {0.f, 0.f, 0.f, 0.f};
    #pragma unroll
    for (int s = 0; s < 16; ++s) {
        if (s + 3 < 16) {                        // issue slice s+3 into buf (s-1)&3
            float* d = xw + ((s + 3) & 3) * 2048;
            GLL(xrow + (s + 3) * 32,     d);
            GLL(xrow + (s + 3) * 32 + 4, d + 256);
        }
        // slice s ready when only the younger slices' loads remain in the FIFO
        if      (s <= 12) asm volatile("s_waitcnt vmcnt(6)" ::: "memory");
        else if (s == 13) asm volatile("s_waitcnt vmcnt(4)" ::: "memory");
        else if (s == 14) asm volatile("s_waitcnt vmcnt(2)" ::: "memory");
        else              asm volatile("s_waitcnt vmcnt(0)" ::: "memory");

        f32x4 lo = *(const f32x4*)(myl + (s & 3) * 2048);        // conflict-free b128
        f32x4 hi = *(const f32x4*)(myl + (s & 3) * 2048 + 256);
        short8 b0 = *(const short8*)(bfr + s * 1024);            // bf16 frag, n = m
        short8 b1 = *(const short8*)(bfr + s * 1024 + 512);      // n = m+16
        short8 a  = cvt8(lo, hi);                                // 4x v_cvt_pk_bf16_f32
        acc0 = __builtin_amdgcn_mfma_f32_16x16x32_bf16(a, b0, acc0, 0, 0, 0);
        acc1 = __builtin_amdgcn_mfma_f32_16x16x32_bf16(a, b1, acc1, 0, 0, 0);
    }

    __syncthreads();   // all waves done with xbuf/wq regions -> safe to alias

    {
        const float bq0 = bq[m];
        const float bq1 = bq[m + 16];
        #pragma unroll
        for (int r = 0; r < 4; ++r) {
            int sidx = wave * 16 + quad * 4 + r;   // local sample (D-row)
            lds_q[sidx][m]      = acc0[r] + bq0;
            lds_q[sidx][m + 16] = acc1[r] + bq1;
        }
    }
    __syncthreads();

    // ============ per-sample tail (round-0 proven): 4 threads / sample ============
    const int sLocal = tid >> 2;       // 0..63
    const int part   = tid & 3;        // owns dims part*8 .. part*8+7
    const int d0     = part * 8;
    const int sample = blockBase + sLocal;

    float q8[8];
    #pragma unroll
    for (int j = 0; j < 8; ++j) q8[j] = lds_q[sLocal][d0 + j];

    float sc[4];
    #pragma unroll
    for (int p = 0; p < 4; ++p) {
        float s = 0.f;
        #pragma unroll
        for (int j = 0; j < 8; ++j) s += q8[j] * pk[p * 32 + d0 + j];
        s += __shfl_xor(s, 1);
        s += __shfl_xor(s, 2);
        sc[p] = s + imp[p];
    }

    const float prob = mprob[sample];
    const float unc  = 1.f - fabsf(prob - 0.5f) * 2.f;
    const float ue   = unc + 1e-8f;
    const float fw   = falpha[0] * ue * ue * ftemp[0];
    const float SCALE = 0.1767766952966369f;   // 32^-0.5
    const float mult  = (1.f + fw) * SCALE;

    float z[4];
    #pragma unroll
    for (int p = 0; p < 4; ++p) z[p] = sc[p] * mult;
    float zmax = fmaxf(fmaxf(z[0], z[1]), fmaxf(z[2], z[3]));
    float w[4], wsum = 0.f;
    #pragma unroll
    for (int p = 0; p < 4; ++p) { w[p] = expf(z[p] - zmax); wsum += w[p]; }
    const float winv = 1.f / wsum;
    #pragma unroll
    for (int p = 0; p < 4; ++p) w[p] *= winv;

    #pragma unroll
    for (int j = 0; j < 8; ++j) {
        float a = 0.f;
        #pragma unroll
        for (int p = 0; p < 4; ++p) a += w[p] * pv[p * 32 + d0 + j];
        lds_att[sLocal][d0 + j] = a;
    }
    __syncthreads();

    float att[32];
    #pragma unroll
    for (int n = 0; n < 32; ++n) att[n] = lds_att[sLocal][n];

    float o[8];
    #pragma unroll
    for (int jo = 0; jo < 8; ++jo) {
        const int n2 = d0 + jo;
        float s = bo[n2];
        #pragma unroll
        for (int n = 0; n < 32; ++n) s += att[n] * Wo[n2 * 32 + n];
        o[jo] = s;
    }

    float s1 = 0.f, s2 = 0.f;
    #pragma unroll
    for (int jo = 0; jo < 8; ++jo) { s1 += o[jo]; s2 += o[jo] * o[jo]; }
    s1 += __shfl_xor(s1, 1); s1 += __shfl_xor(s1, 2);
    s2 += __shfl_xor(s2, 1); s2 += __shfl_xor(s2, 2);
    const float mu   = s1 * (1.f / 32.f);
    const float var  = s2 * (1.f / 32.f) - mu * mu;
    const float rstd = rsqrtf(var + LN_EPS);

    f32x4 res_lo, res_hi;
    #pragma unroll
    for (int jo = 0; jo < 8; ++jo) {
        const int n2 = d0 + jo;
        float y = (o[jo] - mu) * rstd * gamma[n2] + beta[n2];
        if (jo < 4) res_lo[jo] = y; else res_hi[jo - 4] = y;
    }
    *(f32x4*)(out + (size_t)sample * 32 + d0)     = res_lo;
    *(f32x4*)(out + (size_t)sample * 32 + d0 + 4) = res_hi;

    if (part == 0) {
        f32x4 wres;
        #pragma unroll
        for (int p = 0; p < 4; ++p) wres[p] = w[p];
        *(f32x4*)(out + (size_t)B_TOTAL * 32 + (size_t)sample * 4) = wres;
    }
}

extern "C" void kernel_launch(void* const* d_in, const int* in_sizes, int n_in,
                              void* d_out, int out_size, void* d_ws, size_t ws_size,
                              hipStream_t stream) {
    const float* x      = (const float*)d_in[0];
    const float* mprob  = (const float*)d_in[1];
    const float* Wq     = (const float*)d_in[2];
    const float* bq     = (const float*)d_in[3];
    const float* pk     = (const float*)d_in[4];
    const float* pv     = (const float*)d_in[5];
    const float* imp    = (const float*)d_in[6];
    const float* falpha = (const float*)d_in[7];
    const float* ftemp  = (const float*)d_in[8];
    const float* Wo     = (const float*)d_in[9];
    const float* bo     = (const float*)d_in[10];
    const float* gamma  = (const float*)d_in[11];
    const float* beta   = (const float*)d_in[12];
    float* out = (float*)d_out;

    const int blocks = B_TOTAL / 64;   // 4096 blocks, 64 samples each
    faiia_kernel<<<blocks, 256, 0, stream>>>(
        x, mprob, Wq, bq, pk, pv, imp, falpha, ftemp, Wo, bo, gamma, beta, out);
}